// Round 7
// baseline (804.008 us; speedup 1.0000x reference)
//
#include <hip/hip_runtime.h>
#include <hip/hip_bf16.h>
#include <stdint.h>
#include <stddef.h>

// Problem constants (match reference)
#define NB 16       // genes
#define NS 4096     // splice sites per gene
#define NSA 4098    // augmented sites (incl. gene_start, gene_end)
#define NC 512      // channels per site rep
#define NJ 4096     // junctions per gene
#define NT 64       // transcripts per gene
#define NKJ 32      // junctions per transcript
#define KD 1024     // 2*NC = MLP in/hidden dim
#define NM (NB * NJ)  // 65536 rows

// prep kernel block ranges
#define PREP_W_BLKS 2048                    // weight transpose tiles
#define PREP_AUG_BLKS ((NB * NSA) / 4)      // 16392: aug rows / 4
#define PREP_POT_BLKS 64                    // pot zeroing

#define GEMM_BLOCKS 4096

typedef __hip_bfloat16 bf16;
typedef __attribute__((ext_vector_type(8))) short bf16x8;  // 8 bf16 = 4 VGPRs
typedef __attribute__((ext_vector_type(4))) float f32x4;

// GEMM tile geometry: BM=128 x BN=128 x BK=64, 4 waves (2x2),
// 4x4 16x16x32 MFMA per wave. LDS 16B-granule XOR swizzle: logical
// (row m, granule g) stored at slot m*8 + (g ^ (m&7)).
#define BM 128
#define BN 128
#define BK 64

// async global->LDS, 16B per lane. Global address is PER-LANE (gather ok);
// LDS dest = wave-uniform base + lane*16.
__device__ __forceinline__ void gload_lds16(const bf16* g, bf16* l) {
  __builtin_amdgcn_global_load_lds(
      (const __attribute__((address_space(1))) void*)g,
      (__attribute__((address_space(3))) void*)l, 16, 0, 0);
}

// XCD-aware tile swizzle: HW round-robins blockIdx%8 across the 8 XCDs.
// Make the 8 col-blocks that share one 128-row A-stripe land on ONE XCD:
// bid = hi*64 + c*8 + lo  ->  row_idx = hi*8+lo (0..511), col_idx = c (0..7).
// [R6 measured: gemm FETCH 529->85/103 MB, dur 156->138 us. Keep.]
__device__ __forceinline__ void tile_from_bid(int bid, int& row0, int& col0) {
  const int row_idx = ((bid >> 6) << 3) | (bid & 7);  // 0..511
  const int col_idx = (bid >> 3) & 7;                 // 0..7
  row0 = row_idx * BM;
  col0 = col_idx * BN;
}

// ---------------------------------------------------------------------------
// Fused prep kernel, disjoint block ranges:
//   [0, 2048)               : W1/W2 transpose+cast 32x32 tiles -> W1t/W2t
//   [2048, 2048+16392)      : augmented bf16 site table (4 rows/block)
//   [+16392, +16392+64)     : zero pot (+ done-counter)
__global__ void prep_kernel(const float* __restrict__ W1,
                            bf16* __restrict__ W1t,
                            const float* __restrict__ W2,
                            bf16* __restrict__ W2t,
                            const float* __restrict__ ssr,
                            const float* __restrict__ gstart,
                            const float* __restrict__ gend,
                            bf16* __restrict__ aug,
                            float* __restrict__ pot,
                            int* __restrict__ counter) {
  const int bid = blockIdx.x;
  const int tid = threadIdx.x;
  if (bid < PREP_W_BLKS) {
    // ---- weight transpose+cast ----
    __shared__ bf16 tile[32][33];
    const float* W = (bid >= 1024) ? W2 : W1;
    bf16* Wt = (bid >= 1024) ? W2t : W1t;
    const int pos = bid & 1023;
    const int n0 = (pos & 31) * 32;
    const int k0 = (pos >> 5) * 32;
    const int c = tid & 31;
    const int r0 = tid >> 5;  // 0..7
#pragma unroll
    for (int i = 0; i < 4; i++) {
      int r = r0 + i * 8;
      tile[r][c] = __float2bfloat16(W[(size_t)(k0 + r) * KD + (n0 + c)]);
    }
    __syncthreads();
#pragma unroll
    for (int i = 0; i < 4; i++) {
      int r = r0 + i * 8;  // n-row of output
      Wt[(size_t)(n0 + r) * KD + (k0 + c)] = tile[c][r];
    }
  } else if (bid < PREP_W_BLKS + PREP_AUG_BLKS) {
    // ---- aug table: 4 rows per block, one wave per row, dense 16B loads ----
    const int row = (bid - PREP_W_BLKS) * 4 + (tid >> 6);  // 0..NB*NSA-1
    const int i = tid & 63;                                 // lane
    const int b = row / NSA;
    const int s = row - b * NSA;
    const float* src;
    if (s < NS)       src = ssr + ((size_t)b * NS + s) * NC;
    else if (s == NS) src = gstart;
    else              src = gend;
    f32x4 f0 = *(const f32x4*)(src + 4 * i);        // floats [4i, 4i+4)
    f32x4 f1 = *(const f32x4*)(src + 256 + 4 * i);  // floats [256+4i, ..)
    bf16* dst = aug + (size_t)row * NC;
    union { uint64_t u; bf16 e[4]; } a, b4;
    a.e[0] = __float2bfloat16(f0.x); a.e[1] = __float2bfloat16(f0.y);
    a.e[2] = __float2bfloat16(f0.z); a.e[3] = __float2bfloat16(f0.w);
    b4.e[0] = __float2bfloat16(f1.x); b4.e[1] = __float2bfloat16(f1.y);
    b4.e[2] = __float2bfloat16(f1.z); b4.e[3] = __float2bfloat16(f1.w);
    *(uint64_t*)(dst + 4 * i) = a.u;
    *(uint64_t*)(dst + 256 + 4 * i) = b4.u;
  } else {
    // ---- zero pot: 64 blocks x 256 threads x 4 floats = 65536 ----
    const int lb = bid - (PREP_W_BLKS + PREP_AUG_BLKS);
    const int i = lb * 1024 + tid * 4;
    *(f32x4*)(pot + i) = (f32x4){0.f, 0.f, 0.f, 0.f};
    if (lb == 0 && tid == 0) *counter = 0;
  }
}

// ---------------------------------------------------------------------------
// GEMM1 with fused gather via async DMA: A row r = concat(aug[don[r]],
// aug[acc[r]]) in bf16; per-lane gathered global_load_lds addresses.
// C = relu(A @ W1t^T + b1) stored bf16.
__global__ __launch_bounds__(256, 2) void gemm1_gather_kernel(
    const bf16* __restrict__ aug, const int* __restrict__ don,
    const int* __restrict__ acc, const bf16* __restrict__ Bt,
    const float* __restrict__ bias, bf16* __restrict__ Cout) {
  __shared__ __align__(16) bf16 As[BM * BK];
  __shared__ __align__(16) bf16 Bs[BN * BK];
  const int tid = threadIdx.x;
  const int wave = tid >> 6;
  const int lane = tid & 63;
  int row0, col0;
  tile_from_bid(blockIdx.x, row0, col0);
  const int wm = wave & 1;
  const int wn = wave >> 1;
  const int q = lane >> 4;
  const int rr = lane & 15;

  // staging descriptors: LDS slot L covers logical (row m, granule g)
  int mm[4], gg[4];
#pragma unroll
  for (int i = 0; i < 4; i++) {
    int L = wave * 256 + i * 64 + lane;
    int m = L >> 3;
    int g = (L & 7) ^ (m & 7);
    mm[i] = m; gg[i] = g;
  }

  // per-lane gathered A row base pointers (don half / acc half of K)
  const bf16* dp[4];
  const bf16* ap[4];
#pragma unroll
  for (int i = 0; i < 4; i++) {
    const int r = row0 + mm[i];
    const int b = r >> 12;
    dp[i] = aug + ((size_t)b * NSA + don[r]) * NC;
    ap[i] = aug + ((size_t)b * NSA + acc[r]) * NC;
  }

  f32x4 acc4[4][4] = {};

  for (int kt = 0; kt < KD / BK; ++kt) {
    const int ko = (kt & 7) * BK;  // offset within the 512-wide half
#pragma unroll
    for (int i = 0; i < 4; i++) {
      const bf16* abase = (kt < 8) ? dp[i] : ap[i];
      gload_lds16(abase + ko + gg[i] * 8,
                  As + (size_t)(wave * 256 + i * 64) * 8);
      gload_lds16(Bt + ((size_t)(col0 + mm[i]) * KD + kt * BK + gg[i] * 8),
                  Bs + (size_t)(wave * 256 + i * 64) * 8);
    }
    __syncthreads();
#pragma unroll
    for (int kk = 0; kk < 2; ++kk) {
      bf16x8 afr[4], bfr[4];
      const int g = kk * 4 + q;
#pragma unroll
      for (int mt = 0; mt < 4; mt++) {
        int m = wm * 64 + mt * 16 + rr;
        afr[mt] = *(const bf16x8*)(As + (m * 8 + (g ^ (m & 7))) * 8);
      }
#pragma unroll
      for (int nt = 0; nt < 4; nt++) {
        int n = wn * 64 + nt * 16 + rr;
        bfr[nt] = *(const bf16x8*)(Bs + (n * 8 + (g ^ (n & 7))) * 8);
      }
#pragma unroll
      for (int mt = 0; mt < 4; mt++)
#pragma unroll
        for (int nt = 0; nt < 4; nt++)
          acc4[mt][nt] = __builtin_amdgcn_mfma_f32_16x16x32_bf16(
              afr[mt], bfr[nt], acc4[mt][nt], 0, 0, 0);
    }
    __syncthreads();
  }

  // Epilogue. C/D layout: col = lane&15, row = quad*4 + reg
#pragma unroll
  for (int nt = 0; nt < 4; nt++) {
    const int col = col0 + wn * 64 + nt * 16 + rr;
    const float bv = bias[col];
#pragma unroll
    for (int mt = 0; mt < 4; mt++) {
      const int rbase = row0 + wm * 64 + mt * 16 + q * 4;
#pragma unroll
      for (int rg = 0; rg < 4; rg++) {
        float v = fmaxf(acc4[mt][nt][rg] + bv, 0.f);
        Cout[(size_t)(rbase + rg) * KD + col] = __float2bfloat16(v);
      }
    }
  }
}

// ---------------------------------------------------------------------------
// GEMM2 + fused softmax: pot contribution = relu(H1 @ W2t^T + b2) @ w3 via
// atomicAdd; last-to-finish block (device-scope done counter) runs the
// per-gene transcript sum + softmax for all 16 genes.
__global__ __launch_bounds__(256, 2) void gemm2_softmax_kernel(
    const bf16* __restrict__ A, const bf16* __restrict__ Bt,
    const float* __restrict__ bias, const float* __restrict__ w3,
    float* __restrict__ pot, int* __restrict__ counter,
    const int* __restrict__ tj, const float* __restrict__ b3,
    const float* __restrict__ refp, float* __restrict__ out) {
  __shared__ __align__(16) bf16 As[BM * BK];
  __shared__ __align__(16) bf16 Bs[BN * BK];
  const int tid = threadIdx.x;
  const int wave = tid >> 6;
  const int lane = tid & 63;
  int row0, col0;
  tile_from_bid(blockIdx.x, row0, col0);
  const int wm = wave & 1;
  const int wn = wave >> 1;
  const int q = lane >> 4;
  const int rr = lane & 15;

  int mm[4], gg[4];
#pragma unroll
  for (int i = 0; i < 4; i++) {
    int L = wave * 256 + i * 64 + lane;
    int m = L >> 3;
    int g = (L & 7) ^ (m & 7);
    mm[i] = m; gg[i] = g;
  }

  f32x4 acc4[4][4] = {};

  for (int kt = 0; kt < KD / BK; ++kt) {
#pragma unroll
    for (int i = 0; i < 4; i++) {
      gload_lds16(A + ((size_t)(row0 + mm[i]) * KD + kt * BK + gg[i] * 8),
                  As + (size_t)(wave * 256 + i * 64) * 8);
      gload_lds16(Bt + ((size_t)(col0 + mm[i]) * KD + kt * BK + gg[i] * 8),
                  Bs + (size_t)(wave * 256 + i * 64) * 8);
    }
    __syncthreads();
#pragma unroll
    for (int kk = 0; kk < 2; ++kk) {
      bf16x8 afr[4], bfr[4];
      const int g = kk * 4 + q;
#pragma unroll
      for (int mt = 0; mt < 4; mt++) {
        int m = wm * 64 + mt * 16 + rr;
        afr[mt] = *(const bf16x8*)(As + (m * 8 + (g ^ (m & 7))) * 8);
      }
#pragma unroll
      for (int nt = 0; nt < 4; nt++) {
        int n = wn * 64 + nt * 16 + rr;
        bfr[nt] = *(const bf16x8*)(Bs + (n * 8 + (g ^ (n & 7))) * 8);
      }
#pragma unroll
      for (int mt = 0; mt < 4; mt++)
#pragma unroll
        for (int nt = 0; nt < 4; nt++)
          acc4[mt][nt] = __builtin_amdgcn_mfma_f32_16x16x32_bf16(
              afr[mt], bfr[nt], acc4[mt][nt], 0, 0, 0);
    }
    __syncthreads();
  }

  float bv[4], wv[4];
#pragma unroll
  for (int nt = 0; nt < 4; nt++) {
    const int col = col0 + wn * 64 + nt * 16 + rr;
    bv[nt] = bias[col];
    wv[nt] = w3[col];
  }
#pragma unroll
  for (int mt = 0; mt < 4; mt++) {
#pragma unroll
    for (int rg = 0; rg < 4; rg++) {
      float s = 0.f;
#pragma unroll
      for (int nt = 0; nt < 4; nt++)
        s += fmaxf(acc4[mt][nt][rg] + bv[nt], 0.f) * wv[nt];
      s += __shfl_xor(s, 1);
      s += __shfl_xor(s, 2);
      s += __shfl_xor(s, 4);
      s += __shfl_xor(s, 8);
      if (rr == 0) {
        int row = row0 + wm * 64 + mt * 16 + q * 4 + rg;
        atomicAdd(&pot[row], s);
      }
    }
  }

  // ---- done-counter handoff (release: fence before counter RMW) ----
  __threadfence();  // device-scope: pot atomics visible before counter bump
  __shared__ int s_last;
  if (tid == 0) s_last = (atomicAdd(counter, 1) == GEMM_BLOCKS - 1) ? 1 : 0;
  __syncthreads();
  if (s_last == 0) return;

  // ---- last block: acquire, then 16-gene transcript sum + softmax ----
  __threadfence();  // acquire side
  // 4 waves; each wave processes 4 genes; lane t = transcript index
  const int t = lane;
  for (int b = wave; b < NB; b += 4) {
    const int* tjb = tj + ((size_t)b * NT + t) * NKJ;
    float s = 0.f;
#pragma unroll
    for (int k = 0; k < NKJ; k++) {
      // agent-scope atomic load: bypass potentially-stale local caches (G16)
      s += __hip_atomic_load(&pot[b * NJ + tjb[k]], __ATOMIC_RELAXED,
                             __HIP_MEMORY_SCOPE_AGENT);
    }
    s += (float)NKJ * b3[0];
    const float ref = refp[0];
    float m = fmaxf(s, ref);
#pragma unroll
    for (int o = 1; o < 64; o <<= 1) m = fmaxf(m, __shfl_xor(m, o));
    const float e = expf(s - m);
    float denom = e;
#pragma unroll
    for (int o = 1; o < 64; o <<= 1) denom += __shfl_xor(denom, o);
    const float eref = expf(ref - m);
    denom += eref;
    out[b * (NT + 1) + t] = e / denom;
    if (t == 0) out[b * (NT + 1) + NT] = eref / denom;
  }
}

// ---------------------------------------------------------------------------
extern "C" void kernel_launch(void* const* d_in, const int* in_sizes, int n_in,
                              void* d_out, int out_size, void* d_ws,
                              size_t ws_size, hipStream_t stream) {
  const float* ssr    = (const float*)d_in[0];   // [16,4096,512]
  const int*   don    = (const int*)d_in[1];     // [16,4096]
  const int*   acc    = (const int*)d_in[2];     // [16,4096]
  const int*   tj     = (const int*)d_in[3];     // [16,64,32]
  const float* W1     = (const float*)d_in[4];   // [1024,1024]
  const float* b1     = (const float*)d_in[5];   // [1024]
  const float* W2     = (const float*)d_in[6];   // [1024,1024]
  const float* b2     = (const float*)d_in[7];   // [1024]
  const float* W3     = (const float*)d_in[8];   // [1024,1]
  const float* b3     = (const float*)d_in[9];   // [1]
  const float* gstart = (const float*)d_in[10];  // [512]
  const float* gend   = (const float*)d_in[11];  // [512]
  const float* refp   = (const float*)d_in[12];  // [1]
  float* out = (float*)d_out;                    // [16,65]

  // workspace layout (~200 MiB)
  char* ws = (char*)d_ws;
  bf16* W1t = (bf16*)ws;                 ws += (size_t)KD * KD * 2;
  bf16* W2t = (bf16*)ws;                 ws += (size_t)KD * KD * 2;
  bf16* aug = (bf16*)ws;                 ws += (size_t)NB * NSA * NC * 2;
  bf16* H1  = (bf16*)ws;                 ws += (size_t)NM * KD * 2;
  float* pot = (float*)ws;               ws += (size_t)NM * 4;
  int* counter = (int*)ws;               ws += 256;  // done counter

  prep_kernel<<<PREP_W_BLKS + PREP_AUG_BLKS + PREP_POT_BLKS, 256, 0, stream>>>(
      W1, W1t, W2, W2t, ssr, gstart, gend, aug, pot, counter);

  gemm1_gather_kernel<<<GEMM_BLOCKS, 256, 0, stream>>>(aug, don, acc, W1t, b1,
                                                       H1);

  gemm2_softmax_kernel<<<GEMM_BLOCKS, 256, 0, stream>>>(
      H1, W2t, b2, W3, pot, counter, tj, b3, refp, out);
}

// Round 8
// 531.611 us; speedup vs baseline: 1.5124x; 1.5124x over previous
//
#include <hip/hip_runtime.h>
#include <hip/hip_bf16.h>
#include <stdint.h>
#include <stddef.h>

// Problem constants (match reference)
#define NB 16       // genes
#define NS 4096     // splice sites per gene
#define NSA 4098    // augmented sites (incl. gene_start, gene_end)
#define NC 512      // channels per site rep
#define NJ 4096     // junctions per gene
#define NT 64       // transcripts per gene
#define NKJ 32      // junctions per transcript
#define KD 1024     // 2*NC = MLP in/hidden dim
#define NM (NB * NJ)  // 65536 rows

// prep kernel block ranges
#define PREP_W_BLKS 2048                    // weight transpose tiles
#define PREP_AUG_BLKS ((NB * NSA) / 4)      // 16392: aug rows / 4
#define PREP_POT_BLKS 64                    // pot zeroing

#define GEMM_BLOCKS 4096

typedef __hip_bfloat16 bf16;
typedef __attribute__((ext_vector_type(8))) short bf16x8;    // 8 bf16 = 4 VGPRs
typedef __attribute__((ext_vector_type(4))) float f32x4;
typedef __attribute__((ext_vector_type(16))) float f32x16;   // 32x32 C/D frag

// GEMM tile geometry: BM=128 x BN=128 x BK=64, 4 waves (2x2), each wave a
// 64x64 subtile = 2x2 of 32x32x16 MFMA. LDS 16B-granule XOR swizzle:
// logical (row m, granule g) stored at slot m*8 + (g ^ (m&7)).
// [R8: switched 16x16x32 -> 32x32x16: half the MFMA instructions, ~15%
//  higher ubench rate. Frag layouts: C/D col=lane&31,
//  row=(reg&3)+8*(reg>>2)+4*(lane>>5) (m74/m101-verified); A/B
//  m(or n)=lane&31, k=(lane>>5)*8+j.]
#define BM 128
#define BN 128
#define BK 64

// async global->LDS, 16B per lane. Global address is PER-LANE (gather ok);
// LDS dest = wave-uniform base + lane*16.
__device__ __forceinline__ void gload_lds16(const bf16* g, bf16* l) {
  __builtin_amdgcn_global_load_lds(
      (const __attribute__((address_space(1))) void*)g,
      (__attribute__((address_space(3))) void*)l, 16, 0, 0);
}

// XCD-aware tile swizzle: HW round-robins blockIdx%8 across the 8 XCDs.
// Make the 8 col-blocks that share one 128-row A-stripe land on ONE XCD:
// bid = hi*64 + c*8 + lo  ->  row_idx = hi*8+lo (0..511), col_idx = c (0..7).
// [R6 measured: gemm FETCH 529->85/103 MB, dur 156->138 us. Keep.]
__device__ __forceinline__ void tile_from_bid(int bid, int& row0, int& col0) {
  const int row_idx = ((bid >> 6) << 3) | (bid & 7);  // 0..511
  const int col_idx = (bid >> 3) & 7;                 // 0..7
  row0 = row_idx * BM;
  col0 = col_idx * BN;
}

// ---------------------------------------------------------------------------
// Fused prep kernel, disjoint block ranges:
//   [0, 2048)               : W1/W2 transpose+cast 32x32 tiles -> W1t/W2t
//   [2048, 2048+16392)      : augmented bf16 site table (4 rows/block)
//   [+16392, +16392+64)     : zero pot
__global__ void prep_kernel(const float* __restrict__ W1,
                            bf16* __restrict__ W1t,
                            const float* __restrict__ W2,
                            bf16* __restrict__ W2t,
                            const float* __restrict__ ssr,
                            const float* __restrict__ gstart,
                            const float* __restrict__ gend,
                            bf16* __restrict__ aug,
                            float* __restrict__ pot) {
  const int bid = blockIdx.x;
  const int tid = threadIdx.x;
  if (bid < PREP_W_BLKS) {
    // ---- weight transpose+cast ----
    __shared__ bf16 tile[32][33];
    const float* W = (bid >= 1024) ? W2 : W1;
    bf16* Wt = (bid >= 1024) ? W2t : W1t;
    const int pos = bid & 1023;
    const int n0 = (pos & 31) * 32;
    const int k0 = (pos >> 5) * 32;
    const int c = tid & 31;
    const int r0 = tid >> 5;  // 0..7
#pragma unroll
    for (int i = 0; i < 4; i++) {
      int r = r0 + i * 8;
      tile[r][c] = __float2bfloat16(W[(size_t)(k0 + r) * KD + (n0 + c)]);
    }
    __syncthreads();
#pragma unroll
    for (int i = 0; i < 4; i++) {
      int r = r0 + i * 8;  // n-row of output
      Wt[(size_t)(n0 + r) * KD + (k0 + c)] = tile[c][r];
    }
  } else if (bid < PREP_W_BLKS + PREP_AUG_BLKS) {
    // ---- aug table: 4 rows per block, one wave per row, dense 16B loads ----
    const int row = (bid - PREP_W_BLKS) * 4 + (tid >> 6);  // 0..NB*NSA-1
    const int i = tid & 63;                                 // lane
    const int b = row / NSA;
    const int s = row - b * NSA;
    const float* src;
    if (s < NS)       src = ssr + ((size_t)b * NS + s) * NC;
    else if (s == NS) src = gstart;
    else              src = gend;
    f32x4 f0 = *(const f32x4*)(src + 4 * i);        // floats [4i, 4i+4)
    f32x4 f1 = *(const f32x4*)(src + 256 + 4 * i);  // floats [256+4i, ..)
    bf16* dst = aug + (size_t)row * NC;
    union { uint64_t u; bf16 e[4]; } a, b4;
    a.e[0] = __float2bfloat16(f0.x); a.e[1] = __float2bfloat16(f0.y);
    a.e[2] = __float2bfloat16(f0.z); a.e[3] = __float2bfloat16(f0.w);
    b4.e[0] = __float2bfloat16(f1.x); b4.e[1] = __float2bfloat16(f1.y);
    b4.e[2] = __float2bfloat16(f1.z); b4.e[3] = __float2bfloat16(f1.w);
    *(uint64_t*)(dst + 4 * i) = a.u;
    *(uint64_t*)(dst + 256 + 4 * i) = b4.u;
  } else {
    // ---- zero pot: 64 blocks x 256 threads x 4 floats = 65536 ----
    const int i = (bid - (PREP_W_BLKS + PREP_AUG_BLKS)) * 1024 + tid * 4;
    *(f32x4*)(pot + i) = (f32x4){0.f, 0.f, 0.f, 0.f};
  }
}

// ---------------------------------------------------------------------------
// GEMM1 with fused gather via async DMA: A row r = concat(aug[don[r]],
// aug[acc[r]]) in bf16; per-lane gathered global_load_lds addresses.
// C = relu(A @ W1t^T + b1) stored bf16.
__global__ __launch_bounds__(256, 2) void gemm1_gather_kernel(
    const bf16* __restrict__ aug, const int* __restrict__ don,
    const int* __restrict__ acc, const bf16* __restrict__ Bt,
    const float* __restrict__ bias, bf16* __restrict__ Cout) {
  __shared__ __align__(16) bf16 As[BM * BK];
  __shared__ __align__(16) bf16 Bs[BN * BK];
  const int tid = threadIdx.x;
  const int wave = tid >> 6;
  const int lane = tid & 63;
  int row0, col0;
  tile_from_bid(blockIdx.x, row0, col0);
  const int wm = wave & 1;
  const int wn = wave >> 1;
  const int h = lane >> 5;    // half-wave (k-granule select)
  const int l31 = lane & 31;  // row/col within 32x32 tile

  // staging descriptors: LDS slot L covers logical (row m, granule g)
  int mm[4], gg[4];
#pragma unroll
  for (int i = 0; i < 4; i++) {
    int L = wave * 256 + i * 64 + lane;
    int m = L >> 3;
    int g = (L & 7) ^ (m & 7);
    mm[i] = m; gg[i] = g;
  }

  // per-lane gathered A row base pointers (don half / acc half of K)
  const bf16* dp[4];
  const bf16* ap[4];
#pragma unroll
  for (int i = 0; i < 4; i++) {
    const int r = row0 + mm[i];
    const int b = r >> 12;
    dp[i] = aug + ((size_t)b * NSA + don[r]) * NC;
    ap[i] = aug + ((size_t)b * NSA + acc[r]) * NC;
  }

  f32x16 acc4[2][2] = {};

  for (int kt = 0; kt < KD / BK; ++kt) {
    const int ko = (kt & 7) * BK;  // offset within the 512-wide half
#pragma unroll
    for (int i = 0; i < 4; i++) {
      const bf16* abase = (kt < 8) ? dp[i] : ap[i];
      gload_lds16(abase + ko + gg[i] * 8,
                  As + (size_t)(wave * 256 + i * 64) * 8);
      gload_lds16(Bt + ((size_t)(col0 + mm[i]) * KD + kt * BK + gg[i] * 8),
                  Bs + (size_t)(wave * 256 + i * 64) * 8);
    }
    __syncthreads();
#pragma unroll
    for (int kk = 0; kk < 4; ++kk) {  // K=16 per MFMA
      bf16x8 afr[2], bfr[2];
      const int g = kk * 2 + h;
#pragma unroll
      for (int mt = 0; mt < 2; mt++) {
        int m = wm * 64 + mt * 32 + l31;
        afr[mt] = *(const bf16x8*)(As + (m * 8 + (g ^ (m & 7))) * 8);
      }
#pragma unroll
      for (int nt = 0; nt < 2; nt++) {
        int n = wn * 64 + nt * 32 + l31;
        bfr[nt] = *(const bf16x8*)(Bs + (n * 8 + (g ^ (n & 7))) * 8);
      }
#pragma unroll
      for (int mt = 0; mt < 2; mt++)
#pragma unroll
        for (int nt = 0; nt < 2; nt++)
          acc4[mt][nt] = __builtin_amdgcn_mfma_f32_32x32x16_bf16(
              afr[mt], bfr[nt], acc4[mt][nt], 0, 0, 0);
    }
    __syncthreads();
  }

  // Epilogue. C/D layout: col = lane&31, row = (reg&3)+8*(reg>>2)+4*h
#pragma unroll
  for (int nt = 0; nt < 2; nt++) {
    const int col = col0 + wn * 64 + nt * 32 + l31;
    const float bv = bias[col];
#pragma unroll
    for (int mt = 0; mt < 2; mt++) {
      const int rbase = row0 + wm * 64 + mt * 32 + 4 * h;
#pragma unroll
      for (int reg = 0; reg < 16; reg++) {
        const int row = rbase + (reg & 3) + 8 * (reg >> 2);
        float v = fmaxf(acc4[mt][nt][reg] + bv, 0.f);
        Cout[(size_t)row * KD + col] = __float2bfloat16(v);
      }
    }
  }
}

// ---------------------------------------------------------------------------
// GEMM2: pot contribution = relu(H1 @ W2t^T + b2) @ w3, atomicAdd per row.
__global__ __launch_bounds__(256, 2) void gemm2_kernel(
    const bf16* __restrict__ A, const bf16* __restrict__ Bt,
    const float* __restrict__ bias, const float* __restrict__ w3,
    float* __restrict__ pot) {
  __shared__ __align__(16) bf16 As[BM * BK];
  __shared__ __align__(16) bf16 Bs[BN * BK];
  const int tid = threadIdx.x;
  const int wave = tid >> 6;
  const int lane = tid & 63;
  int row0, col0;
  tile_from_bid(blockIdx.x, row0, col0);
  const int wm = wave & 1;
  const int wn = wave >> 1;
  const int h = lane >> 5;
  const int l31 = lane & 31;

  int mm[4], gg[4];
#pragma unroll
  for (int i = 0; i < 4; i++) {
    int L = wave * 256 + i * 64 + lane;
    int m = L >> 3;
    int g = (L & 7) ^ (m & 7);
    mm[i] = m; gg[i] = g;
  }

  f32x16 acc4[2][2] = {};

  for (int kt = 0; kt < KD / BK; ++kt) {
#pragma unroll
    for (int i = 0; i < 4; i++) {
      gload_lds16(A + ((size_t)(row0 + mm[i]) * KD + kt * BK + gg[i] * 8),
                  As + (size_t)(wave * 256 + i * 64) * 8);
      gload_lds16(Bt + ((size_t)(col0 + mm[i]) * KD + kt * BK + gg[i] * 8),
                  Bs + (size_t)(wave * 256 + i * 64) * 8);
    }
    __syncthreads();
#pragma unroll
    for (int kk = 0; kk < 4; ++kk) {
      bf16x8 afr[2], bfr[2];
      const int g = kk * 2 + h;
#pragma unroll
      for (int mt = 0; mt < 2; mt++) {
        int m = wm * 64 + mt * 32 + l31;
        afr[mt] = *(const bf16x8*)(As + (m * 8 + (g ^ (m & 7))) * 8);
      }
#pragma unroll
      for (int nt = 0; nt < 2; nt++) {
        int n = wn * 64 + nt * 32 + l31;
        bfr[nt] = *(const bf16x8*)(Bs + (n * 8 + (g ^ (n & 7))) * 8);
      }
#pragma unroll
      for (int mt = 0; mt < 2; mt++)
#pragma unroll
        for (int nt = 0; nt < 2; nt++)
          acc4[mt][nt] = __builtin_amdgcn_mfma_f32_32x32x16_bf16(
              afr[mt], bfr[nt], acc4[mt][nt], 0, 0, 0);
    }
    __syncthreads();
  }

  float bv[2], wv[2];
#pragma unroll
  for (int nt = 0; nt < 2; nt++) {
    const int col = col0 + wn * 64 + nt * 32 + l31;
    bv[nt] = bias[col];
    wv[nt] = w3[col];
  }
#pragma unroll
  for (int mt = 0; mt < 2; mt++) {
#pragma unroll
    for (int reg = 0; reg < 16; reg++) {
      float s = 0.f;
#pragma unroll
      for (int nt = 0; nt < 2; nt++)
        s += fmaxf(acc4[mt][nt][reg] + bv[nt], 0.f) * wv[nt];
      // reduce across the 32 lanes (cols) of this half-wave's 32x32 tile
      s += __shfl_xor(s, 1);
      s += __shfl_xor(s, 2);
      s += __shfl_xor(s, 4);
      s += __shfl_xor(s, 8);
      s += __shfl_xor(s, 16);
      if (l31 == 0) {
        const int row =
            row0 + wm * 64 + mt * 32 + (reg & 3) + 8 * (reg >> 2) + 4 * h;
        atomicAdd(&pot[row], s);
      }
    }
  }
}

// ---------------------------------------------------------------------------
// Per-gene transcript potential sum + softmax over T+1 entries.
__global__ void transcript_softmax_kernel(const float* __restrict__ pot,
                                          const int* __restrict__ tj,
                                          const float* __restrict__ b3,
                                          const float* __restrict__ refp,
                                          float* __restrict__ out) {
  const int b = blockIdx.x;
  const int t = threadIdx.x;  // 64 threads = 1 wave
  const int* tjb = tj + ((size_t)b * NT + t) * NKJ;
  float s = 0.f;
#pragma unroll
  for (int k = 0; k < NKJ; k++) s += pot[b * NJ + tjb[k]];
  s += (float)NKJ * b3[0];
  const float ref = refp[0];
  float m = fmaxf(s, ref);
#pragma unroll
  for (int o = 1; o < 64; o <<= 1) m = fmaxf(m, __shfl_xor(m, o));
  const float e = expf(s - m);
  float denom = e;
#pragma unroll
  for (int o = 1; o < 64; o <<= 1) denom += __shfl_xor(denom, o);
  const float eref = expf(ref - m);
  denom += eref;
  out[b * (NT + 1) + t] = e / denom;
  if (t == 0) out[b * (NT + 1) + NT] = eref / denom;
}

// ---------------------------------------------------------------------------
extern "C" void kernel_launch(void* const* d_in, const int* in_sizes, int n_in,
                              void* d_out, int out_size, void* d_ws,
                              size_t ws_size, hipStream_t stream) {
  const float* ssr    = (const float*)d_in[0];   // [16,4096,512]
  const int*   don    = (const int*)d_in[1];     // [16,4096]
  const int*   acc    = (const int*)d_in[2];     // [16,4096]
  const int*   tj     = (const int*)d_in[3];     // [16,64,32]
  const float* W1     = (const float*)d_in[4];   // [1024,1024]
  const float* b1     = (const float*)d_in[5];   // [1024]
  const float* W2     = (const float*)d_in[6];   // [1024,1024]
  const float* b2     = (const float*)d_in[7];   // [1024]
  const float* W3     = (const float*)d_in[8];   // [1024,1]
  const float* b3     = (const float*)d_in[9];   // [1]
  const float* gstart = (const float*)d_in[10];  // [512]
  const float* gend   = (const float*)d_in[11];  // [512]
  const float* refp   = (const float*)d_in[12];  // [1]
  float* out = (float*)d_out;                    // [16,65]

  // workspace layout (~200 MiB)
  char* ws = (char*)d_ws;
  bf16* W1t = (bf16*)ws;                 ws += (size_t)KD * KD * 2;
  bf16* W2t = (bf16*)ws;                 ws += (size_t)KD * KD * 2;
  bf16* aug = (bf16*)ws;                 ws += (size_t)NB * NSA * NC * 2;
  bf16* H1  = (bf16*)ws;                 ws += (size_t)NM * KD * 2;
  float* pot = (float*)ws;               ws += (size_t)NM * 4;

  prep_kernel<<<PREP_W_BLKS + PREP_AUG_BLKS + PREP_POT_BLKS, 256, 0, stream>>>(
      W1, W1t, W2, W2t, ssr, gstart, gend, aug, pot);

  gemm1_gather_kernel<<<GEMM_BLOCKS, 256, 0, stream>>>(aug, don, acc, W1t, b1,
                                                       H1);

  gemm2_kernel<<<GEMM_BLOCKS, 256, 0, stream>>>(H1, W2t, b2, W3, pot);

  transcript_softmax_kernel<<<NB, 64, 0, stream>>>(pot, tj, b3, refp, out);
}